// Round 19
// baseline (179.960 us; speedup 1.0000x reference)
//
#include <hip/hip_runtime.h>
#include <hip/hip_bf16.h>
#include <stdint.h>

typedef short short8 __attribute__((ext_vector_type(8)));
typedef float f32x4 __attribute__((ext_vector_type(4)));

#define BQ 4
#define NSEQ 2048
#define DMODEL 1024
#define NHEAD 16
#define HDIM 64
#define MTOT 8192          // BQ*NSEQ
#define QKV_LD 3072

#if __has_builtin(__builtin_amdgcn_exp2f)
#define EXP2(x) __builtin_amdgcn_exp2f(x)
#else
#define EXP2(x) exp2f(x)
#endif
#define C_SCL 0.18033688f   // 0.125 * log2(e)
#define THR_RAW 16.635532f  // 3.0 / C_SCL : defer-max threshold (P bounded by 2^3)

__device__ __forceinline__ uint16_t f2bf(float f) {
  uint32_t u = __builtin_bit_cast(uint32_t, f);
  uint32_t r = (u + 0x7FFFu + ((u >> 16) & 1u)) >> 16;
  return (uint16_t)r;
}
// hardware RNE convert (v_cvt_pk_bf16_f32 after compiler fusion)
__device__ __forceinline__ uint16_t f2bf_hw(float f) {
  __hip_bfloat16 h = __float2bfloat16(f);
  return __builtin_bit_cast(uint16_t, h);
}

// Single prep kernel = cast(x) + transpose(w_attn) + transpose(w_proj).
__global__ void prep_k(const float* __restrict__ x, uint16_t* __restrict__ xb,
                       const float* __restrict__ w_attn, uint16_t* __restrict__ wat,
                       const float* __restrict__ w_proj, uint16_t* __restrict__ wpt) {
  __shared__ float tile[32][33];
  const int bid = blockIdx.x;
  if (bid < 2048) {
    // cast x [8192*1024] f32 -> bf16
    int idx = (bid * 256 + threadIdx.x) * 4;
    const int stride = 2048 * 256 * 4;
    for (int i = idx; i < MTOT * DMODEL; i += stride) {
      float4 v = *reinterpret_cast<const float4*>(x + i);
      ushort4 o;
      o.x = f2bf(v.x); o.y = f2bf(v.y); o.z = f2bf(v.z); o.w = f2bf(v.w);
      *reinterpret_cast<ushort4*>(xb + i) = o;
    }
    return;
  }
  // transpose+cast: in [K=1024][N] f32 -> out [N][K] bf16
  const float* in; uint16_t* out; int N, t;
  if (bid < 2048 + 3072) { in = w_attn; out = wat; N = 3072; t = bid - 2048; }
  else                   { in = w_proj; out = wpt; N = 1024; t = bid - 5120; }
  const int K = 1024;
  const int nb = N / 32;
  const int n0 = (t % nb) * 32;
  const int k0 = (t / nb) * 32;
  const int tx = threadIdx.x & 31;
  const int ty = threadIdx.x >> 5;
#pragma unroll
  for (int r = 0; r < 4; ++r)
    tile[ty + r * 8][tx] = in[(size_t)(k0 + ty + r * 8) * N + n0 + tx];
  __syncthreads();
#pragma unroll
  for (int r = 0; r < 4; ++r)
    out[(size_t)(n0 + ty + r * 8) * K + k0 + tx] = f2bf(tile[tx][ty + r * 8]);
}

// C[M,N] = A[M,K] @ BT[N,K]^T ; A,BT bf16 row-major. 128x128 tile, BK=64.
// Pre-swizzled global source (m173): row r's LDS slot s holds global k-chunk
// s ^ (r&7); reader uses slot (kk*4+lq) ^ (l16&7). Measured: -10% vs BK=32.
// NOTE: GEMM keeps __syncthreads() — its staged data lands in LDS, so the
// vmcnt(0) drain before the barrier is semantically required here.
template <bool BF16_OUT>
__global__ void __launch_bounds__(256, 3)
gemm_bt_k(const uint16_t* __restrict__ A, const uint16_t* __restrict__ BT,
          void* __restrict__ Cout, const float* __restrict__ bias,
          int M, int N, int K) {
  __shared__ uint16_t As[128 * 64];
  __shared__ uint16_t Bs[128 * 64];
  const int tid = threadIdx.x;
  const int lane = tid & 63;
  const int wave = tid >> 6;
  const int wr = wave >> 1, wc = wave & 1;   // wave -> 64x64 quadrant
  const int brow = blockIdx.y * 128;
  const int bcol = blockIdx.x * 128;
  const int l16 = lane & 15;
  const int lq = lane >> 4;

  f32x4 acc[4][4];
  const f32x4 fzero = {0.f, 0.f, 0.f, 0.f};
#pragma unroll
  for (int i = 0; i < 4; ++i)
#pragma unroll
    for (int j = 0; j < 4; ++j) acc[i][j] = fzero;

  // staging: 1024 16B-chunks per 128x64 tile; chunk c -> row c>>3, slot c&7;
  // slot holds global k-chunk (c&7) ^ (row&7). LDS linear at c*8 elems.
  size_t gA0, gA1, gA2, gA3, gB0, gB1, gB2, gB3;
  int ls0, ls1, ls2, ls3;
  {
    int c0 = tid, c1 = tid + 256, c2 = tid + 512, c3 = tid + 768;
    int r0 = c0 >> 3, r1 = c1 >> 3, r2 = c2 >> 3, r3 = c3 >> 3;
    int k0 = (c0 & 7) ^ (r0 & 7), k1 = (c1 & 7) ^ (r1 & 7);
    int k2 = (c2 & 7) ^ (r2 & 7), k3 = (c3 & 7) ^ (r3 & 7);
    gA0 = (size_t)(brow + r0) * K + k0 * 8;  gB0 = (size_t)(bcol + r0) * K + k0 * 8;
    gA1 = (size_t)(brow + r1) * K + k1 * 8;  gB1 = (size_t)(bcol + r1) * K + k1 * 8;
    gA2 = (size_t)(brow + r2) * K + k2 * 8;  gB2 = (size_t)(bcol + r2) * K + k2 * 8;
    gA3 = (size_t)(brow + r3) * K + k3 * 8;  gB3 = (size_t)(bcol + r3) * K + k3 * 8;
    ls0 = c0 * 8; ls1 = c1 * 8; ls2 = c2 * 8; ls3 = c3 * 8;
  }

#define GLD(PTR, OFF, LDSARR, LS)                                               \
  __builtin_amdgcn_global_load_lds(                                             \
      (const __attribute__((address_space(1))) void*)((PTR) + (OFF)),           \
      (__attribute__((address_space(3))) void*)&LDSARR[LS], 16, 0, 0)

  for (int kt = 0; kt < K; kt += 64) {
    GLD(A, gA0 + kt, As, ls0);
    GLD(A, gA1 + kt, As, ls1);
    GLD(A, gA2 + kt, As, ls2);
    GLD(A, gA3 + kt, As, ls3);
    GLD(BT, gB0 + kt, Bs, ls0);
    GLD(BT, gB1 + kt, Bs, ls1);
    GLD(BT, gB2 + kt, Bs, ls2);
    GLD(BT, gB3 + kt, Bs, ls3);
    __syncthreads();   // vmcnt(0) drain required: data lands in LDS
#pragma unroll
    for (int kk = 0; kk < 2; ++kk) {
      short8 af[4], bfr[4];
#pragma unroll
      for (int r = 0; r < 4; ++r) {
        const int rowA = wr * 64 + r * 16 + l16;
        const int rowB = wc * 64 + r * 16 + l16;
        const int slot = (kk * 4 + lq) ^ (l16 & 7);   // (row&7) == (l16&7)
        af[r]  = *reinterpret_cast<const short8*>(&As[rowA * 64 + slot * 8]);
        bfr[r] = *reinterpret_cast<const short8*>(&Bs[rowB * 64 + slot * 8]);
      }
#pragma unroll
      for (int r = 0; r < 4; ++r)
#pragma unroll
        for (int c = 0; c < 4; ++c)
          acc[r][c] = __builtin_amdgcn_mfma_f32_16x16x32_bf16(af[r], bfr[c], acc[r][c], 0, 0, 0);
    }
    __syncthreads();
  }
#undef GLD

#pragma unroll
  for (int r = 0; r < 4; ++r) {
    const int row0 = brow + wr * 64 + r * 16 + lq * 4;
#pragma unroll
    for (int c = 0; c < 4; ++c) {
      const int col = bcol + wc * 64 + c * 16 + l16;
#pragma unroll
      for (int i = 0; i < 4; ++i) {
        if constexpr (BF16_OUT)
          reinterpret_cast<uint16_t*>(Cout)[(size_t)(row0 + i) * N + col] = f2bf_hw(acc[r][c][i]);
        else
          reinterpret_cast<float*>(Cout)[(size_t)(row0 + i) * N + col] = acc[r][c][i] + bias[col];
      }
    }
  }
}

// Flash attention, causal. qkv [MTOT][3072] bf16 (q|k|v), out [MTOT][1024] bf16.
// Round-13 structure + ROUND-19: COUNTED-VMCNT BARRIERS (T4 applied to attn).
// __syncthreads() emits s_waitcnt vmcnt(0) before s_barrier — draining the jt+1
// REGISTER prefetch (issued just before the barrier) to completion every iter:
// ~200-300 cyc of L2 latency on the serial chain, 33x per block. The prefetch
// lands in REGISTERS (not LDS), so the barrier has no semantic need for vmcnt;
// the consume point (next iter's commit) gets a compiler-inserted vmcnt wait.
// Fix: raw s_barrier; top barrier preceded by lgkmcnt(0) only (ds_writes must
// be visible); end barrier needs no waitcnt (all ds_reads consumed by MFMAs
// before it). sched_barrier(0) fences pin ordering (rule #18).
__global__ void __launch_bounds__(256, 3)
attn_fwd_k(const uint16_t* __restrict__ qkv, uint16_t* __restrict__ outb) {
  const int obid = blockIdx.x;
  const int bid = (obid & 7) * 128 + (obid >> 3);   // T1: contiguous 128-block chunk per XCD
  const int p = bid & 15;
  const int h = (bid >> 4) & 15;
  const int b = bid >> 8;
  const int qtA = p;
  const int qtB = 31 - p;
  const int tid = threadIdx.x;
  const int lane = tid & 63;
  const int w = tid >> 6;
  const int l16 = lane & 15;
  const int lq = lane >> 4;

  __shared__ uint16_t Ks[64 * 72];         // [token][d], stride 72
  __shared__ uint16_t Vt[64 * 72];         // [d][sigma-permuted token], stride 72

  // Q fragments for both q-tiles (row=l16, k=8*lq+j per 32-d chunk)
  short8 qaA0, qaA1, qaB0, qaB1;
  {
    const size_t baseA = ((size_t)(b * NSEQ + qtA * 64 + w * 16 + l16)) * QKV_LD + h * 64 + lq * 8;
    const size_t baseB = ((size_t)(b * NSEQ + qtB * 64 + w * 16 + l16)) * QKV_LD + h * 64 + lq * 8;
    qaA0 = *reinterpret_cast<const short8*>(qkv + baseA);
    qaA1 = *reinterpret_cast<const short8*>(qkv + baseA + 32);
    qaB0 = *reinterpret_cast<const short8*>(qkv + baseB);
    qaB1 = *reinterpret_cast<const short8*>(qkv + baseB + 32);
  }

  float mA = -1e30f, lA = 0.f, mB = -1e30f, lB = 0.f;
  f32x4 accA[4], accB[4];
  const f32x4 fzero = {0.f, 0.f, 0.f, 0.f};
#pragma unroll
  for (int i = 0; i < 4; ++i) { accA[i] = fzero; accB[i] = fzero; }

  // staging geometry: 512 chunks, chunk c -> token row c>>3, d-off (c&7)*8
  const int r0 = tid >> 3, d0 = (tid & 7) * 8;
  const int ka0 = r0 * 72 + d0;
  const int ka1 = (r0 + 32) * 72 + d0;
  const int lqt = (r0 >> 2) & 3;
  const int nc0 = r0 >> 4;
  const int m0 = d0 >> 3;
  const int jo = (nc0 & 1) * 4 + (r0 & 3);
  const int vcol0 = (((2 * lqt) ^ m0) * 8) + jo;        // token r0  -> pa0 chunk
  const int vcol1 = (((2 * lqt + 1) ^ m0) * 8) + jo;    // token r0+32 -> pa1 chunk

  const int ntiles = qtB + 1;
  short8 rk0, rk1, rv0, rv1;
  {
    const size_t g0 = ((size_t)(b * NSEQ + r0)) * QKV_LD + 1024 + h * 64 + d0;
    const size_t g1 = ((size_t)(b * NSEQ + r0 + 32)) * QKV_LD + 1024 + h * 64 + d0;
    rk0 = *reinterpret_cast<const short8*>(qkv + g0);
    rv0 = *reinterpret_cast<const short8*>(qkv + g0 + 1024);
    rk1 = *reinterpret_cast<const short8*>(qkv + g1);
    rv1 = *reinterpret_cast<const short8*>(qkv + g1 + 1024);
  }

#define SOFTMAX_PV(SV, M_I, L_I, ACC, DIAG)                                     \
  {                                                                             \
    float tmax_;                                                                \
    if (DIAG) {                                                                 \
      float tm_[4];                                                             \
      _Pragma("unroll") for (int nc = 0; nc < 4; ++nc) {                        \
        float a_ = -3e38f, b_ = -3e38f;                                         \
        _Pragma("unroll") for (int i = 0; i < 4; ++i) {                         \
          float v_ = SV[nc][i];                                                 \
          if ((nc * 16 + lq * 4 + i) > (w * 16 + l16)) v_ = -3e38f;             \
          SV[nc][i] = v_;                                                       \
          if (i < 2) a_ = fmaxf(a_, v_); else b_ = fmaxf(b_, v_);               \
        }                                                                       \
        tm_[nc] = fmaxf(a_, b_);                                                \
      }                                                                         \
      tmax_ = fmaxf(fmaxf(tm_[0], tm_[1]), fmaxf(tm_[2], tm_[3]));              \
    } else {                                                                    \
      float tm_[4];                                                             \
      _Pragma("unroll") for (int nc = 0; nc < 4; ++nc)                          \
        tm_[nc] = fmaxf(fmaxf(SV[nc][0], SV[nc][1]),                            \
                        fmaxf(SV[nc][2], SV[nc][3]));                           \
      tmax_ = fmaxf(fmaxf(tm_[0], tm_[1]), fmaxf(tm_[2], tm_[3]));              \
    }                                                                           \
    tmax_ = fmaxf(tmax_, __shfl_xor(tmax_, 16, 64));                            \
    tmax_ = fmaxf(tmax_, __shfl_xor(tmax_, 32, 64));                            \
    if (!__all(tmax_ <= M_I + THR_RAW)) {                                       \
      const float mn_ = fmaxf(M_I, tmax_);                                      \
      const float alpha_ = EXP2((M_I - mn_) * C_SCL);                           \
      M_I = mn_;                                                                \
      L_I *= alpha_;                                                            \
      float ab_[4];                                                             \
      _Pragma("unroll") for (int i = 0; i < 4; ++i)                             \
        ab_[i] = __shfl(alpha_, lq * 4 + i, 64);                                \
      _Pragma("unroll") for (int d4 = 0; d4 < 4; ++d4)                          \
        _Pragma("unroll") for (int i = 0; i < 4; ++i)                           \
          ACC[d4][i] *= ab_[i];                                                 \
    }                                                                           \
    const float mc_ = M_I * C_SCL;                                              \
    float rs_[4];                                                               \
    short8 pa0_, pa1_;                                                          \
    _Pragma("unroll") for (int nc = 0; nc < 4; ++nc) {                          \
      float pvv_[4];                                                            \
      _Pragma("unroll") for (int i = 0; i < 4; ++i) {                           \
        float pv_ = EXP2(__builtin_fmaf(SV[nc][i], C_SCL, -mc_));               \
        pvv_[i] = pv_;                                                          \
        uint16_t ph_ = f2bf_hw(pv_);                                            \
        if (nc < 2) pa0_[nc * 4 + i] = (short)ph_;                              \
        else        pa1_[(nc - 2) * 4 + i] = (short)ph_;                        \
      }                                                                         \
      rs_[nc] = (pvv_[0] + pvv_[1]) + (pvv_[2] + pvv_[3]);                      \
    }                                                                           \
    float rsum_ = (rs_[0] + rs_[1]) + (rs_[2] + rs_[3]);                        \
    rsum_ += __shfl_xor(rsum_, 16, 64);                                         \
    rsum_ += __shfl_xor(rsum_, 32, 64);                                         \
    L_I += rsum_;                                                               \
    _Pragma("unroll") for (int d4 = 0; d4 < 4; ++d4) {                          \
      const int drow_ = d4 * 16 + l16;                                          \
      const int xr_ = (drow_ >> 3) & 7;                                         \
      short8 vb0_ = *reinterpret_cast<const short8*>(&Vt[drow_ * 72 + (((2 * lq) ^ xr_) * 8)]); \
      short8 vb1_ = *reinterpret_cast<const short8*>(&Vt[drow_ * 72 + (((2 * lq + 1) ^ xr_) * 8)]); \
      ACC[d4] = __builtin_amdgcn_mfma_f32_16x16x32_bf16(pa0_, vb0_, ACC[d4], 0, 0, 0); \
      ACC[d4] = __builtin_amdgcn_mfma_f32_16x16x32_bf16(pa1_, vb1_, ACC[d4], 0, 0, 0); \
    }                                                                           \
  }

  for (int jt = 0; jt < ntiles; ++jt) {
    // --- commit staged regs to LDS (prev compute finished at loop-end barrier) ---
    *reinterpret_cast<short8*>(&Ks[ka0]) = rk0;
    *reinterpret_cast<short8*>(&Ks[ka1]) = rk1;
#pragma unroll
    for (int j = 0; j < 8; ++j) Vt[(d0 + j) * 72 + vcol0] = (uint16_t)rv0[j];
#pragma unroll
    for (int j = 0; j < 8; ++j) Vt[(d0 + j) * 72 + vcol1] = (uint16_t)rv1[j];
    // --- issue next tile's global loads; these stay IN FLIGHT across the barrier ---
    if (jt + 1 < ntiles) {
      const size_t g0 = ((size_t)(b * NSEQ + (jt + 1) * 64 + r0)) * QKV_LD + 1024 + h * 64 + d0;
      const size_t g1 = ((size_t)(b * NSEQ + (jt + 1) * 64 + r0 + 32)) * QKV_LD + 1024 + h * 64 + d0;
      rk0 = *reinterpret_cast<const short8*>(qkv + g0);
      rv0 = *reinterpret_cast<const short8*>(qkv + g0 + 1024);
      rk1 = *reinterpret_cast<const short8*>(qkv + g1);
      rv1 = *reinterpret_cast<const short8*>(qkv + g1 + 1024);
    }
    // top barrier: ds_writes must be visible (lgkmcnt(0)); vmcnt NOT drained —
    // the register prefetch is consumed next iter with a compiler vmcnt wait.
    asm volatile("s_waitcnt lgkmcnt(0)" ::: "memory");
    __builtin_amdgcn_sched_barrier(0);
    __builtin_amdgcn_s_barrier();
    __builtin_amdgcn_sched_barrier(0);

    // --- tile B: S^T = K Q^T, softmax, PV ---
    {
      f32x4 sv[4];
#pragma unroll
      for (int nc = 0; nc < 4; ++nc) {
        short8 kb0 = *reinterpret_cast<const short8*>(&Ks[(nc * 16 + l16) * 72 + lq * 8]);
        short8 kb1 = *reinterpret_cast<const short8*>(&Ks[(nc * 16 + l16) * 72 + 32 + lq * 8]);
        f32x4 s = fzero;
        s = __builtin_amdgcn_mfma_f32_16x16x32_bf16(kb0, qaB0, s, 0, 0, 0);
        s = __builtin_amdgcn_mfma_f32_16x16x32_bf16(kb1, qaB1, s, 0, 0, 0);
        sv[nc] = s;
      }
      SOFTMAX_PV(sv, mB, lB, accB, jt == qtB);
    }

    // --- tile A (active while jt <= qtA) ---
    if (jt <= qtA) {
      f32x4 sv[4];
#pragma unroll
      for (int nc = 0; nc < 4; ++nc) {
        short8 kb0 = *reinterpret_cast<const short8*>(&Ks[(nc * 16 + l16) * 72 + lq * 8]);
        short8 kb1 = *reinterpret_cast<const short8*>(&Ks[(nc * 16 + l16) * 72 + 32 + lq * 8]);
        f32x4 s = fzero;
        s = __builtin_amdgcn_mfma_f32_16x16x32_bf16(kb0, qaA0, s, 0, 0, 0);
        s = __builtin_amdgcn_mfma_f32_16x16x32_bf16(kb1, qaA1, s, 0, 0, 0);
        sv[nc] = s;
      }
      SOFTMAX_PV(sv, mA, lA, accA, jt == qtA);
    }

    // end barrier: all this iter's ds_reads already consumed by MFMAs (compiler
    // lgkm waits precede each MFMA), so no waitcnt needed before s_barrier.
    __builtin_amdgcn_sched_barrier(0);
    __builtin_amdgcn_s_barrier();
    __builtin_amdgcn_sched_barrier(0);
  }

  // epilogue: l for acc row q = lq*4 + i lives at lane l16 = q
  {
    float lb4[4];
#pragma unroll
    for (int i = 0; i < 4; ++i) lb4[i] = __shfl(lA, lq * 4 + i, 64);
    const size_t orow = (size_t)(b * NSEQ) + qtA * 64 + w * 16 + lq * 4;
#pragma unroll
    for (int d4 = 0; d4 < 4; ++d4)
#pragma unroll
      for (int i = 0; i < 4; ++i)
        outb[(orow + i) * (size_t)DMODEL + h * 64 + d4 * 16 + l16] = f2bf_hw(accA[d4][i] / lb4[i]);
  }
  {
    float lb4[4];
#pragma unroll
    for (int i = 0; i < 4; ++i) lb4[i] = __shfl(lB, lq * 4 + i, 64);
    const size_t orow = (size_t)(b * NSEQ) + qtB * 64 + w * 16 + lq * 4;
#pragma unroll
    for (int d4 = 0; d4 < 4; ++d4)
#pragma unroll
      for (int i = 0; i < 4; ++i)
        outb[(orow + i) * (size_t)DMODEL + h * 64 + d4 * 16 + l16] = f2bf_hw(accB[d4][i] / lb4[i]);
  }
}

extern "C" void kernel_launch(void* const* d_in, const int* in_sizes, int n_in,
                              void* d_out, int out_size, void* d_ws, size_t ws_size,
                              hipStream_t stream) {
  const float* x      = (const float*)d_in[0];
  const float* w_attn = (const float*)d_in[1];
  const float* w_proj = (const float*)d_in[2];
  const float* b_proj = (const float*)d_in[3];

  uint16_t* xb    = (uint16_t*)d_ws;                    // [8192][1024]
  uint16_t* wat   = xb   + (size_t)MTOT * DMODEL;       // [3072][1024] (w_attn^T)
  uint16_t* wpt   = wat  + (size_t)3072 * 1024;         // [1024][1024] (w_proj^T)
  uint16_t* qkvb  = wpt  + (size_t)1024 * 1024;         // [8192][3072]
  uint16_t* attnb = qkvb + (size_t)MTOT * QKV_LD;       // [8192][1024]

  prep_k<<<2048 + 3072 + 1024, 256, 0, stream>>>(x, xb, w_attn, wat, w_proj, wpt);

  gemm_bt_k<true><<<dim3(3072 / 128, MTOT / 128), 256, 0, stream>>>(
      xb, wat, qkvb, nullptr, MTOT, 3072, 1024);

  attn_fwd_k<<<BQ * NHEAD * 16, 256, 0, stream>>>(qkvb, attnb);

  gemm_bt_k<false><<<dim3(1024 / 128, MTOT / 128), 256, 0, stream>>>(
      attnb, wpt, d_out, b_proj, MTOT, 1024, 1024);
}

// Round 20
// 177.795 us; speedup vs baseline: 1.0122x; 1.0122x over previous
//
#include <hip/hip_runtime.h>
#include <hip/hip_bf16.h>
#include <stdint.h>

typedef short short8 __attribute__((ext_vector_type(8)));
typedef float f32x4 __attribute__((ext_vector_type(4)));

#define BQ 4
#define NSEQ 2048
#define DMODEL 1024
#define NHEAD 16
#define HDIM 64
#define MTOT 8192          // BQ*NSEQ
#define QKV_LD 3072

#if __has_builtin(__builtin_amdgcn_exp2f)
#define EXP2(x) __builtin_amdgcn_exp2f(x)
#else
#define EXP2(x) exp2f(x)
#endif
#define C_SCL 0.18033688f   // 0.125 * log2(e)
#define THR_RAW 16.635532f  // 3.0 / C_SCL : defer-max threshold (P bounded by 2^3)

__device__ __forceinline__ uint16_t f2bf(float f) {
  uint32_t u = __builtin_bit_cast(uint32_t, f);
  uint32_t r = (u + 0x7FFFu + ((u >> 16) & 1u)) >> 16;
  return (uint16_t)r;
}
// hardware RNE convert (v_cvt_pk_bf16_f32 after compiler fusion)
__device__ __forceinline__ uint16_t f2bf_hw(float f) {
  __hip_bfloat16 h = __float2bfloat16(f);
  return __builtin_bit_cast(uint16_t, h);
}

// Single prep kernel = cast(x) + transpose(w_attn) + transpose(w_proj).
__global__ void prep_k(const float* __restrict__ x, uint16_t* __restrict__ xb,
                       const float* __restrict__ w_attn, uint16_t* __restrict__ wat,
                       const float* __restrict__ w_proj, uint16_t* __restrict__ wpt) {
  __shared__ float tile[32][33];
  const int bid = blockIdx.x;
  if (bid < 2048) {
    // cast x [8192*1024] f32 -> bf16
    int idx = (bid * 256 + threadIdx.x) * 4;
    const int stride = 2048 * 256 * 4;
    for (int i = idx; i < MTOT * DMODEL; i += stride) {
      float4 v = *reinterpret_cast<const float4*>(x + i);
      ushort4 o;
      o.x = f2bf(v.x); o.y = f2bf(v.y); o.z = f2bf(v.z); o.w = f2bf(v.w);
      *reinterpret_cast<ushort4*>(xb + i) = o;
    }
    return;
  }
  // transpose+cast: in [K=1024][N] f32 -> out [N][K] bf16
  const float* in; uint16_t* out; int N, t;
  if (bid < 2048 + 3072) { in = w_attn; out = wat; N = 3072; t = bid - 2048; }
  else                   { in = w_proj; out = wpt; N = 1024; t = bid - 5120; }
  const int K = 1024;
  const int nb = N / 32;
  const int n0 = (t % nb) * 32;
  const int k0 = (t / nb) * 32;
  const int tx = threadIdx.x & 31;
  const int ty = threadIdx.x >> 5;
#pragma unroll
  for (int r = 0; r < 4; ++r)
    tile[ty + r * 8][tx] = in[(size_t)(k0 + ty + r * 8) * N + n0 + tx];
  __syncthreads();
#pragma unroll
  for (int r = 0; r < 4; ++r)
    out[(size_t)(n0 + ty + r * 8) * K + k0 + tx] = f2bf(tile[tx][ty + r * 8]);
}

// C[M,N] = A[M,K] @ BT[N,K]^T ; A,BT bf16 row-major. 128x128 tile, BK=64.
// Halves the K-iterations (32->16) so the structure's defining stall (vmcnt(0)
// drain before each barrier) amortizes over 2x MFMA work; LDS 32KB keeps
// 3 blocks/CU. Bank fix per m173: pre-swizzled global source — row r's LDS slot
// s holds global k-chunk s ^ (r&7); reader uses slot (kk*4+lq) ^ (l16&7).
// Measured round 17: GEMMs -10% vs BK=32.
template <bool BF16_OUT>
__global__ void __launch_bounds__(256, 3)
gemm_bt_k(const uint16_t* __restrict__ A, const uint16_t* __restrict__ BT,
          void* __restrict__ Cout, const float* __restrict__ bias,
          int M, int N, int K) {
  __shared__ uint16_t As[128 * 64];
  __shared__ uint16_t Bs[128 * 64];
  const int tid = threadIdx.x;
  const int lane = tid & 63;
  const int wave = tid >> 6;
  const int wr = wave >> 1, wc = wave & 1;   // wave -> 64x64 quadrant
  const int brow = blockIdx.y * 128;
  const int bcol = blockIdx.x * 128;
  const int l16 = lane & 15;
  const int lq = lane >> 4;

  f32x4 acc[4][4];
  const f32x4 fzero = {0.f, 0.f, 0.f, 0.f};
#pragma unroll
  for (int i = 0; i < 4; ++i)
#pragma unroll
    for (int j = 0; j < 4; ++j) acc[i][j] = fzero;

  // staging: 1024 16B-chunks per 128x64 tile; chunk c -> row c>>3, slot c&7;
  // slot holds global k-chunk (c&7) ^ (row&7). LDS linear at c*8 elems.
  size_t gA0, gA1, gA2, gA3, gB0, gB1, gB2, gB3;
  int ls0, ls1, ls2, ls3;
  {
    int c0 = tid, c1 = tid + 256, c2 = tid + 512, c3 = tid + 768;
    int r0 = c0 >> 3, r1 = c1 >> 3, r2 = c2 >> 3, r3 = c3 >> 3;
    int k0 = (c0 & 7) ^ (r0 & 7), k1 = (c1 & 7) ^ (r1 & 7);
    int k2 = (c2 & 7) ^ (r2 & 7), k3 = (c3 & 7) ^ (r3 & 7);
    gA0 = (size_t)(brow + r0) * K + k0 * 8;  gB0 = (size_t)(bcol + r0) * K + k0 * 8;
    gA1 = (size_t)(brow + r1) * K + k1 * 8;  gB1 = (size_t)(bcol + r1) * K + k1 * 8;
    gA2 = (size_t)(brow + r2) * K + k2 * 8;  gB2 = (size_t)(bcol + r2) * K + k2 * 8;
    gA3 = (size_t)(brow + r3) * K + k3 * 8;  gB3 = (size_t)(bcol + r3) * K + k3 * 8;
    ls0 = c0 * 8; ls1 = c1 * 8; ls2 = c2 * 8; ls3 = c3 * 8;
  }

#define GLD(PTR, OFF, LDSARR, LS)                                               \
  __builtin_amdgcn_global_load_lds(                                             \
      (const __attribute__((address_space(1))) void*)((PTR) + (OFF)),           \
      (__attribute__((address_space(3))) void*)&LDSARR[LS], 16, 0, 0)

  for (int kt = 0; kt < K; kt += 64) {
    GLD(A, gA0 + kt, As, ls0);
    GLD(A, gA1 + kt, As, ls1);
    GLD(A, gA2 + kt, As, ls2);
    GLD(A, gA3 + kt, As, ls3);
    GLD(BT, gB0 + kt, Bs, ls0);
    GLD(BT, gB1 + kt, Bs, ls1);
    GLD(BT, gB2 + kt, Bs, ls2);
    GLD(BT, gB3 + kt, Bs, ls3);
    __syncthreads();   // vmcnt(0) drain required: data lands in LDS
#pragma unroll
    for (int kk = 0; kk < 2; ++kk) {
      short8 af[4], bfr[4];
#pragma unroll
      for (int r = 0; r < 4; ++r) {
        const int rowA = wr * 64 + r * 16 + l16;
        const int rowB = wc * 64 + r * 16 + l16;
        const int slot = (kk * 4 + lq) ^ (l16 & 7);   // (row&7) == (l16&7)
        af[r]  = *reinterpret_cast<const short8*>(&As[rowA * 64 + slot * 8]);
        bfr[r] = *reinterpret_cast<const short8*>(&Bs[rowB * 64 + slot * 8]);
      }
#pragma unroll
      for (int r = 0; r < 4; ++r)
#pragma unroll
        for (int c = 0; c < 4; ++c)
          acc[r][c] = __builtin_amdgcn_mfma_f32_16x16x32_bf16(af[r], bfr[c], acc[r][c], 0, 0, 0);
    }
    __syncthreads();
  }
#undef GLD

#pragma unroll
  for (int r = 0; r < 4; ++r) {
    const int row0 = brow + wr * 64 + r * 16 + lq * 4;
#pragma unroll
    for (int c = 0; c < 4; ++c) {
      const int col = bcol + wc * 64 + c * 16 + l16;
#pragma unroll
      for (int i = 0; i < 4; ++i) {
        if constexpr (BF16_OUT)
          reinterpret_cast<uint16_t*>(Cout)[(size_t)(row0 + i) * N + col] = f2bf_hw(acc[r][c][i]);
        else
          reinterpret_cast<float*>(Cout)[(size_t)(row0 + i) * N + col] = acc[r][c][i] + bias[col];
      }
    }
  }
}

// Flash attention, causal. qkv [MTOT][3072] bf16 (q|k|v), out [MTOT][1024] bf16.
// FINAL (round-18 state, best measured 178.8us total / 85.6us attn):
// T1 XCD swizzle (FETCH 152->24.6MB), paired q-tiles (flat 33-iter blocks),
// A/B sequential per iter (one sv[4] live -> no spill), swapped QK^T (row-local
// softmax: 15 local max + 2 shfl), P-in-register via sigma-permuted V layout
// (no P LDS round-trip), uniform-diag branch, T13 defer-max, raw-S exp2-fma,
// hw bf16 cvt, unrounded f32 rsum, tree-reassociated reductions, async-STAGE.
// Plateau notes: NOT a HW roofline (MfmaUtil 17%, HBM 6%) — latency plateau of
// the 4-wave/16-row structure; 8 structural levers measured at <=+-3% (R10-R19).
__global__ void __launch_bounds__(256, 3)
attn_fwd_k(const uint16_t* __restrict__ qkv, uint16_t* __restrict__ outb) {
  const int obid = blockIdx.x;
  const int bid = (obid & 7) * 128 + (obid >> 3);   // T1: contiguous 128-block chunk per XCD
  const int p = bid & 15;
  const int h = (bid >> 4) & 15;
  const int b = bid >> 8;
  const int qtA = p;
  const int qtB = 31 - p;
  const int tid = threadIdx.x;
  const int lane = tid & 63;
  const int w = tid >> 6;
  const int l16 = lane & 15;
  const int lq = lane >> 4;

  __shared__ uint16_t Ks[64 * 72];         // [token][d], stride 72
  __shared__ uint16_t Vt[64 * 72];         // [d][sigma-permuted token], stride 72

  // Q fragments for both q-tiles (row=l16, k=8*lq+j per 32-d chunk)
  short8 qaA0, qaA1, qaB0, qaB1;
  {
    const size_t baseA = ((size_t)(b * NSEQ + qtA * 64 + w * 16 + l16)) * QKV_LD + h * 64 + lq * 8;
    const size_t baseB = ((size_t)(b * NSEQ + qtB * 64 + w * 16 + l16)) * QKV_LD + h * 64 + lq * 8;
    qaA0 = *reinterpret_cast<const short8*>(qkv + baseA);
    qaA1 = *reinterpret_cast<const short8*>(qkv + baseA + 32);
    qaB0 = *reinterpret_cast<const short8*>(qkv + baseB);
    qaB1 = *reinterpret_cast<const short8*>(qkv + baseB + 32);
  }

  float mA = -1e30f, lA = 0.f, mB = -1e30f, lB = 0.f;
  f32x4 accA[4], accB[4];
  const f32x4 fzero = {0.f, 0.f, 0.f, 0.f};
#pragma unroll
  for (int i = 0; i < 4; ++i) { accA[i] = fzero; accB[i] = fzero; }

  // staging geometry: 512 chunks, chunk c -> token row c>>3, d-off (c&7)*8
  const int r0 = tid >> 3, d0 = (tid & 7) * 8;
  const int ka0 = r0 * 72 + d0;
  const int ka1 = (r0 + 32) * 72 + d0;
  const int lqt = (r0 >> 2) & 3;
  const int nc0 = r0 >> 4;
  const int m0 = d0 >> 3;
  const int jo = (nc0 & 1) * 4 + (r0 & 3);
  const int vcol0 = (((2 * lqt) ^ m0) * 8) + jo;        // token r0  -> pa0 chunk
  const int vcol1 = (((2 * lqt + 1) ^ m0) * 8) + jo;    // token r0+32 -> pa1 chunk

  const int ntiles = qtB + 1;
  short8 rk0, rk1, rv0, rv1;
  {
    const size_t g0 = ((size_t)(b * NSEQ + r0)) * QKV_LD + 1024 + h * 64 + d0;
    const size_t g1 = ((size_t)(b * NSEQ + r0 + 32)) * QKV_LD + 1024 + h * 64 + d0;
    rk0 = *reinterpret_cast<const short8*>(qkv + g0);
    rv0 = *reinterpret_cast<const short8*>(qkv + g0 + 1024);
    rk1 = *reinterpret_cast<const short8*>(qkv + g1);
    rv1 = *reinterpret_cast<const short8*>(qkv + g1 + 1024);
  }

#define SOFTMAX_PV(SV, M_I, L_I, ACC, DIAG)                                     \
  {                                                                             \
    float tmax_;                                                                \
    if (DIAG) {                                                                 \
      float tm_[4];                                                             \
      _Pragma("unroll") for (int nc = 0; nc < 4; ++nc) {                        \
        float a_ = -3e38f, b_ = -3e38f;                                         \
        _Pragma("unroll") for (int i = 0; i < 4; ++i) {                         \
          float v_ = SV[nc][i];                                                 \
          if ((nc * 16 + lq * 4 + i) > (w * 16 + l16)) v_ = -3e38f;             \
          SV[nc][i] = v_;                                                       \
          if (i < 2) a_ = fmaxf(a_, v_); else b_ = fmaxf(b_, v_);               \
        }                                                                       \
        tm_[nc] = fmaxf(a_, b_);                                                \
      }                                                                         \
      tmax_ = fmaxf(fmaxf(tm_[0], tm_[1]), fmaxf(tm_[2], tm_[3]));              \
    } else {                                                                    \
      float tm_[4];                                                             \
      _Pragma("unroll") for (int nc = 0; nc < 4; ++nc)                          \
        tm_[nc] = fmaxf(fmaxf(SV[nc][0], SV[nc][1]),                            \
                        fmaxf(SV[nc][2], SV[nc][3]));                           \
      tmax_ = fmaxf(fmaxf(tm_[0], tm_[1]), fmaxf(tm_[2], tm_[3]));              \
    }                                                                           \
    tmax_ = fmaxf(tmax_, __shfl_xor(tmax_, 16, 64));                            \
    tmax_ = fmaxf(tmax_, __shfl_xor(tmax_, 32, 64));                            \
    if (!__all(tmax_ <= M_I + THR_RAW)) {                                       \
      const float mn_ = fmaxf(M_I, tmax_);                                      \
      const float alpha_ = EXP2((M_I - mn_) * C_SCL);                           \
      M_I = mn_;                                                                \
      L_I *= alpha_;                                                            \
      float ab_[4];                                                             \
      _Pragma("unroll") for (int i = 0; i < 4; ++i)                             \
        ab_[i] = __shfl(alpha_, lq * 4 + i, 64);                                \
      _Pragma("unroll") for (int d4 = 0; d4 < 4; ++d4)                          \
        _Pragma("unroll") for (int i = 0; i < 4; ++i)                           \
          ACC[d4][i] *= ab_[i];                                                 \
    }                                                                           \
    const float mc_ = M_I * C_SCL;                                              \
    float rs_[4];                                                               \
    short8 pa0_, pa1_;                                                          \
    _Pragma("unroll") for (int nc = 0; nc < 4; ++nc) {                          \
      float pvv_[4];                                                            \
      _Pragma("unroll") for (int i = 0; i < 4; ++i) {                           \
        float pv_ = EXP2(__builtin_fmaf(SV[nc][i], C_SCL, -mc_));               \
        pvv_[i] = pv_;                                                          \
        uint16_t ph_ = f2bf_hw(pv_);                                            \
        if (nc < 2) pa0_[nc * 4 + i] = (short)ph_;                              \
        else        pa1_[(nc - 2) * 4 + i] = (short)ph_;                        \
      }                                                                         \
      rs_[nc] = (pvv_[0] + pvv_[1]) + (pvv_[2] + pvv_[3]);                      \
    }                                                                           \
    float rsum_ = (rs_[0] + rs_[1]) + (rs_[2] + rs_[3]);                        \
    rsum_ += __shfl_xor(rsum_, 16, 64);                                         \
    rsum_ += __shfl_xor(rsum_, 32, 64);                                         \
    L_I += rsum_;                                                               \
    _Pragma("unroll") for (int d4 = 0; d4 < 4; ++d4) {                          \
      const int drow_ = d4 * 16 + l16;                                          \
      const int xr_ = (drow_ >> 3) & 7;                                         \
      short8 vb0_ = *reinterpret_cast<const short8*>(&Vt[drow_ * 72 + (((2 * lq) ^ xr_) * 8)]); \
      short8 vb1_ = *reinterpret_cast<const short8*>(&Vt[drow_ * 72 + (((2 * lq + 1) ^ xr_) * 8)]); \
      ACC[d4] = __builtin_amdgcn_mfma_f32_16x16x32_bf16(pa0_, vb0_, ACC[d4], 0, 0, 0); \
      ACC[d4] = __builtin_amdgcn_mfma_f32_16x16x32_bf16(pa1_, vb1_, ACC[d4], 0, 0, 0); \
    }                                                                           \
  }

  for (int jt = 0; jt < ntiles; ++jt) {
    // --- commit staged regs to LDS (prev compute finished at loop-end barrier) ---
    *reinterpret_cast<short8*>(&Ks[ka0]) = rk0;
    *reinterpret_cast<short8*>(&Ks[ka1]) = rk1;
#pragma unroll
    for (int j = 0; j < 8; ++j) Vt[(d0 + j) * 72 + vcol0] = (uint16_t)rv0[j];
#pragma unroll
    for (int j = 0; j < 8; ++j) Vt[(d0 + j) * 72 + vcol1] = (uint16_t)rv1[j];
    // --- issue next tile's global loads; latency hides under this tile's compute ---
    if (jt + 1 < ntiles) {
      const size_t g0 = ((size_t)(b * NSEQ + (jt + 1) * 64 + r0)) * QKV_LD + 1024 + h * 64 + d0;
      const size_t g1 = ((size_t)(b * NSEQ + (jt + 1) * 64 + r0 + 32)) * QKV_LD + 1024 + h * 64 + d0;
      rk0 = *reinterpret_cast<const short8*>(qkv + g0);
      rv0 = *reinterpret_cast<const short8*>(qkv + g0 + 1024);
      rk1 = *reinterpret_cast<const short8*>(qkv + g1);
      rv1 = *reinterpret_cast<const short8*>(qkv + g1 + 1024);
    }
    __syncthreads();

    // --- tile B: S^T = K Q^T, softmax, PV ---
    {
      f32x4 sv[4];
#pragma unroll
      for (int nc = 0; nc < 4; ++nc) {
        short8 kb0 = *reinterpret_cast<const short8*>(&Ks[(nc * 16 + l16) * 72 + lq * 8]);
        short8 kb1 = *reinterpret_cast<const short8*>(&Ks[(nc * 16 + l16) * 72 + 32 + lq * 8]);
        f32x4 s = fzero;
        s = __builtin_amdgcn_mfma_f32_16x16x32_bf16(kb0, qaB0, s, 0, 0, 0);
        s = __builtin_amdgcn_mfma_f32_16x16x32_bf16(kb1, qaB1, s, 0, 0, 0);
        sv[nc] = s;
      }
      SOFTMAX_PV(sv, mB, lB, accB, jt == qtB);
    }

    // --- tile A (active while jt <= qtA) ---
    if (jt <= qtA) {
      f32x4 sv[4];
#pragma unroll
      for (int nc = 0; nc < 4; ++nc) {
        short8 kb0 = *reinterpret_cast<const short8*>(&Ks[(nc * 16 + l16) * 72 + lq * 8]);
        short8 kb1 = *reinterpret_cast<const short8*>(&Ks[(nc * 16 + l16) * 72 + 32 + lq * 8]);
        f32x4 s = fzero;
        s = __builtin_amdgcn_mfma_f32_16x16x32_bf16(kb0, qaA0, s, 0, 0, 0);
        s = __builtin_amdgcn_mfma_f32_16x16x32_bf16(kb1, qaA1, s, 0, 0, 0);
        sv[nc] = s;
      }
      SOFTMAX_PV(sv, mA, lA, accA, jt == qtA);
    }

    __syncthreads();   // protect Ks/Vt before next stage-commit
  }

  // epilogue: l for acc row q = lq*4 + i lives at lane l16 = q
  {
    float lb4[4];
#pragma unroll
    for (int i = 0; i < 4; ++i) lb4[i] = __shfl(lA, lq * 4 + i, 64);
    const size_t orow = (size_t)(b * NSEQ) + qtA * 64 + w * 16 + lq * 4;
#pragma unroll
    for (int d4 = 0; d4 < 4; ++d4)
#pragma unroll
      for (int i = 0; i < 4; ++i)
        outb[(orow + i) * (size_t)DMODEL + h * 64 + d4 * 16 + l16] = f2bf_hw(accA[d4][i] / lb4[i]);
  }
  {
    float lb4[4];
#pragma unroll
    for (int i = 0; i < 4; ++i) lb4[i] = __shfl(lB, lq * 4 + i, 64);
    const size_t orow = (size_t)(b * NSEQ) + qtB * 64 + w * 16 + lq * 4;
#pragma unroll
    for (int d4 = 0; d4 < 4; ++d4)
#pragma unroll
      for (int i = 0; i < 4; ++i)
        outb[(orow + i) * (size_t)DMODEL + h * 64 + d4 * 16 + l16] = f2bf_hw(accB[d4][i] / lb4[i]);
  }
}

extern "C" void kernel_launch(void* const* d_in, const int* in_sizes, int n_in,
                              void* d_out, int out_size, void* d_ws, size_t ws_size,
                              hipStream_t stream) {
  const float* x      = (const float*)d_in[0];
  const float* w_attn = (const float*)d_in[1];
  const float* w_proj = (const float*)d_in[2];
  const float* b_proj = (const float*)d_in[3];

  uint16_t* xb    = (uint16_t*)d_ws;                    // [8192][1024]
  uint16_t* wat   = xb   + (size_t)MTOT * DMODEL;       // [3072][1024] (w_attn^T)
  uint16_t* wpt   = wat  + (size_t)3072 * 1024;         // [1024][1024] (w_proj^T)
  uint16_t* qkvb  = wpt  + (size_t)1024 * 1024;         // [8192][3072]
  uint16_t* attnb = qkvb + (size_t)MTOT * QKV_LD;       // [8192][1024]

  prep_k<<<2048 + 3072 + 1024, 256, 0, stream>>>(x, xb, w_attn, wat, w_proj, wpt);

  gemm_bt_k<true><<<dim3(3072 / 128, MTOT / 128), 256, 0, stream>>>(
      xb, wat, qkvb, nullptr, MTOT, 3072, 1024);

  attn_fwd_k<<<BQ * NHEAD * 16, 256, 0, stream>>>(qkvb, attnb);

  gemm_bt_k<false><<<dim3(1024 / 128, MTOT / 128), 256, 0, stream>>>(
      attnb, wpt, d_out, b_proj, MTOT, 1024, 1024);
}